// Round 1
// baseline (2140.080 us; speedup 1.0000x reference)
//
#include <hip/hip_runtime.h>

// Problem constants
#define NB 16
#define NH 64
#define NW 64
#define ND 128
#define NK 4096
#define NROWS (NB * NH * NW)        // 65536
#define NSLICE 4
#define SLICE_K (NK / NSLICE)       // 1024
#define OUT_ELEMS (NB * ND * NH * NW)  // 8388608

// ---------------------------------------------------------------------------
// Kernel 1: enorm[k] = ||emb[k]||^2   (one wave per code)
// ---------------------------------------------------------------------------
__global__ void enorm_kernel(const float* __restrict__ emb,
                             float* __restrict__ enorm) {
    int wave = (blockIdx.x * blockDim.x + threadIdx.x) >> 6;
    int lane = threadIdx.x & 63;
    if (wave >= NK) return;
    const float* e = emb + (size_t)wave * ND;
    float a = e[lane];
    float b = e[lane + 64];
    float s = a * a + b * b;
#pragma unroll
    for (int off = 32; off > 0; off >>= 1) s += __shfl_down(s, off, 64);
    if (lane == 0) enorm[wave] = s;
}

// ---------------------------------------------------------------------------
// Kernel 2: argmin. One block per 64-row group. Lane = row (z row in VGPRs),
// wave = code slice (emb row is wave-uniform -> s_load broadcast).
// score_k = ||e_k||^2 - 2 z.e_k  (||z||^2 constant per row, dropped)
// ---------------------------------------------------------------------------
__global__ void argmin_kernel(const float* __restrict__ z,
                              const float* __restrict__ emb,
                              const float* __restrict__ enorm,
                              int* __restrict__ idx_out) {
    // z staging tile: 64 rows x 128 d, stride 132 floats (16B-aligned rows)
    __shared__ float zs[64 * 132];
    __shared__ float red_min[NSLICE * 64];
    __shared__ int red_idx[NSLICE * 64];

    const int bid = blockIdx.x;            // 0..1023 row-group
    const int rowbase = bid * 64;
    const int t = threadIdx.x;

    // Cooperative coalesced stage of z tile into LDS (2048 float4)
    const float4* zg = (const float4*)(z + (size_t)rowbase * ND);
#pragma unroll
    for (int q = 0; q < 8; q++) {
        int i = t + 256 * q;               // 0..2047
        float4 v = zg[i];
        int r = i >> 5;                    // 32 float4 per row
        int d4 = (i & 31) << 2;
        float4* p = (float4*)&zs[r * 132 + d4];
        *p = v;
    }
    __syncthreads();

    const int lane = t & 63;
    const int wid = __builtin_amdgcn_readfirstlane(t >> 6);  // wave-uniform slice id

    // Pull this lane's z row into registers (one-time cost)
    float zr[ND];
#pragma unroll
    for (int d = 0; d < ND; d++) zr[d] = zs[lane * 132 + d];

    float best = 3.4e38f;
    int bidx = 0;
    const int k0 = wid * SLICE_K;
    for (int k = k0; k < k0 + SLICE_K; k++) {
        const float* __restrict__ e = emb + k * ND;  // wave-uniform address
        float a0 = 0.f, a1 = 0.f, a2 = 0.f, a3 = 0.f;
#pragma unroll
        for (int d = 0; d < ND; d += 4) {
            a0 = fmaf(zr[d + 0], e[d + 0], a0);
            a1 = fmaf(zr[d + 1], e[d + 1], a1);
            a2 = fmaf(zr[d + 2], e[d + 2], a2);
            a3 = fmaf(zr[d + 3], e[d + 3], a3);
        }
        float dot = (a0 + a1) + (a2 + a3);
        float s = enorm[k] - 2.0f * dot;   // enorm[k]: wave-uniform scalar load
        if (s < best) { best = s; bidx = k; }  // strict < keeps first index
    }

    red_min[wid * 64 + lane] = best;
    red_idx[wid * 64 + lane] = bidx;
    __syncthreads();

    if (wid == 0) {
        float bm = red_min[lane];
        int bi = red_idx[lane];
#pragma unroll
        for (int sl = 1; sl < NSLICE; sl++) {
            float m = red_min[sl * 64 + lane];
            int i2 = red_idx[sl * 64 + lane];
            if (m < bm) { bm = m; bi = i2; }  // ascending slice order => first-idx ties
        }
        idx_out[rowbase + lane] = bi;
    }
}

// ---------------------------------------------------------------------------
// Kernel 3: gather + loss partial + transposed write.
// One block per (b,h): 64 w-positions x 128 d.
// ---------------------------------------------------------------------------
__global__ void out_kernel(const float* __restrict__ z,
                           const float* __restrict__ emb,
                           const int* __restrict__ idx,
                           float* __restrict__ out,
                           float* __restrict__ losspart) {
    __shared__ float zq[64 * 129];
    __shared__ int ids[64];
    __shared__ float redl[4];

    const int bid = blockIdx.x;         // b*64 + h
    const int b = bid >> 6;
    const int h = bid & 63;
    const int rowbase = bid * 64;
    const int t = threadIdx.x;

    if (t < 64) ids[t] = idx[rowbase + t];
    __syncthreads();

    // Pass A: coalesced z reads, emb gather (wave-uniform row), loss accum,
    // fill zq tile in LDS.
    const int d = t & 127;
    const int w0 = t >> 7;
    float lsum = 0.f;
#pragma unroll
    for (int wq = 0; wq < 32; wq++) {
        int w = w0 + 2 * wq;
        float e = emb[(size_t)ids[w] * ND + d];
        float zv = z[((size_t)(rowbase + w)) * ND + d];
        float df = e - zv;
        lsum = fmaf(df, df, lsum);
        zq[w * 129 + d] = e;
    }
#pragma unroll
    for (int off = 32; off > 0; off >>= 1) lsum += __shfl_down(lsum, off, 64);
    if ((t & 63) == 0) redl[t >> 6] = lsum;
    __syncthreads();    // also fences zq writes for pass B
    if (t == 0) losspart[bid] = redl[0] + redl[1] + redl[2] + redl[3];

    // Pass B: out[b][d][h][w], lanes sweep w -> coalesced 256B stores.
    const int w = t & 63;
    const int dq = t >> 6;
#pragma unroll
    for (int dd0 = 0; dd0 < 32; dd0++) {
        int dd = dq + 4 * dd0;
        out[(((size_t)b * ND + dd) * NH + h) * NW + w] = zq[w * 129 + dd];
    }
}

// ---------------------------------------------------------------------------
// Kernel 4: final loss reduce
// ---------------------------------------------------------------------------
__global__ void loss_kernel(const float* __restrict__ losspart,
                            float* __restrict__ out) {
    __shared__ float redl[4];
    const int t = threadIdx.x;
    float s = 0.f;
#pragma unroll
    for (int i = 0; i < 4; i++) s += losspart[t + 256 * i];
#pragma unroll
    for (int off = 32; off > 0; off >>= 1) s += __shfl_down(s, off, 64);
    if ((t & 63) == 0) redl[t >> 6] = s;
    __syncthreads();
    if (t == 0) {
        float total = redl[0] + redl[1] + redl[2] + redl[3];
        out[OUT_ELEMS] = 1.25f * total / (float)OUT_ELEMS;
    }
}

// ---------------------------------------------------------------------------
extern "C" void kernel_launch(void* const* d_in, const int* in_sizes, int n_in,
                              void* d_out, int out_size, void* d_ws, size_t ws_size,
                              hipStream_t stream) {
    const float* z = (const float*)d_in[0];      // [16,64,64,128] fp32
    const float* emb = (const float*)d_in[1];    // [4096,128] fp32
    float* out = (float*)d_out;                  // 8388608 + 1 fp32

    char* ws = (char*)d_ws;
    int* ws_idx = (int*)ws;                          // NROWS ints   (256 KB)
    float* ws_enorm = (float*)(ws + 262144);         // NK floats    (16 KB)
    float* ws_losspart = (float*)(ws + 262144 + 16384);  // 1024 floats

    enorm_kernel<<<NK / 4, 256, 0, stream>>>(emb, ws_enorm);
    argmin_kernel<<<NROWS / 64, 256, 0, stream>>>(z, emb, ws_enorm, ws_idx);
    out_kernel<<<NB * NH, 256, 0, stream>>>(z, emb, ws_idx, out, ws_losspart);
    loss_kernel<<<1, 256, 0, stream>>>(ws_losspart, out);
}

// Round 2
// 1769.999 us; speedup vs baseline: 1.2091x; 1.2091x over previous
//
#include <hip/hip_runtime.h>

// Problem constants
#define NB 16
#define NH 64
#define NW 64
#define ND 128
#define NK 4096
#define NROWS (NB * NH * NW)        // 65536
#define NSLICE 4
#define SLICE_K (NK / NSLICE)       // 1024
#define OUT_ELEMS (NB * ND * NH * NW)  // 8388608

// ---------------------------------------------------------------------------
// Kernel 1: enorm[k] = ||emb[k]||^2   (one wave per code)
// ---------------------------------------------------------------------------
__global__ void enorm_kernel(const float* __restrict__ emb,
                             float* __restrict__ enorm) {
    int wave = (blockIdx.x * blockDim.x + threadIdx.x) >> 6;
    int lane = threadIdx.x & 63;
    if (wave >= NK) return;
    const float* e = emb + (size_t)wave * ND;
    float a = e[lane];
    float b = e[lane + 64];
    float s = a * a + b * b;
#pragma unroll
    for (int off = 32; off > 0; off >>= 1) s += __shfl_down(s, off, 64);
    if (lane == 0) enorm[wave] = s;
}

// ---------------------------------------------------------------------------
// Kernel 2: argmin. One block per 64-row group. Lane = row (z row in VGPRs),
// wave = code slice (emb row is wave-uniform -> scalar-load broadcast).
// score_k = ||e_k||^2 - 2 z.e_k  (||z||^2 constant per row, dropped)
// __launch_bounds__(256, 2): cap at 2 waves/EU so the 128-float z row stays
// register-resident (R1 showed the default 64-VGPR budget spilled it to
// scratch: VGPR_Count=64, WRITE_SIZE=33MB, VALUBusy=23%).
// ---------------------------------------------------------------------------
__global__ void __launch_bounds__(256, 2)
argmin_kernel(const float* __restrict__ z,
              const float* __restrict__ emb,
              const float* __restrict__ enorm,
              int* __restrict__ idx_out) {
    // z staging tile: 64 rows x 128 d, stride 132 floats (16B-aligned rows)
    __shared__ float zs[64 * 132];
    __shared__ float red_min[NSLICE * 64];
    __shared__ int red_idx[NSLICE * 64];

    const int bid = blockIdx.x;            // 0..1023 row-group
    const int rowbase = bid * 64;
    const int t = threadIdx.x;

    // Cooperative coalesced stage of z tile into LDS (2048 float4)
    const float4* zg = (const float4*)(z + (size_t)rowbase * ND);
#pragma unroll
    for (int q = 0; q < 8; q++) {
        int i = t + 256 * q;               // 0..2047
        float4 v = zg[i];
        int r = i >> 5;                    // 32 float4 per row
        int d4 = (i & 31) << 2;
        float4* p = (float4*)&zs[r * 132 + d4];
        *p = v;
    }
    __syncthreads();

    const int lane = t & 63;
    const int wid = __builtin_amdgcn_readfirstlane(t >> 6);  // wave-uniform slice id

    // Pull this lane's z row into registers (float4 -> ds_read_b128)
    float4 zr4[32];
    {
        const float4* zrow = (const float4*)&zs[lane * 132];
#pragma unroll
        for (int d = 0; d < 32; d++) zr4[d] = zrow[d];
    }

    float best = 3.4e38f;
    int bidx = 0;
    const int k0 = wid * SLICE_K;
    for (int k = k0; k < k0 + SLICE_K; k++) {
        const float4* __restrict__ e4 = (const float4*)(emb + (size_t)k * ND);
        float a0 = 0.f, a1 = 0.f, a2 = 0.f, a3 = 0.f;
#pragma unroll
        for (int d = 0; d < 32; d++) {
            float4 ev = e4[d];             // wave-uniform -> s_load broadcast
            float4 zv = zr4[d];
            a0 = fmaf(zv.x, ev.x, a0);
            a1 = fmaf(zv.y, ev.y, a1);
            a2 = fmaf(zv.z, ev.z, a2);
            a3 = fmaf(zv.w, ev.w, a3);
        }
        float dot = (a0 + a1) + (a2 + a3);
        float s = enorm[k] - 2.0f * dot;   // enorm[k]: wave-uniform scalar load
        if (s < best) { best = s; bidx = k; }  // strict < keeps first index
    }

    red_min[wid * 64 + lane] = best;
    red_idx[wid * 64 + lane] = bidx;
    __syncthreads();

    if (wid == 0) {
        float bm = red_min[lane];
        int bi = red_idx[lane];
#pragma unroll
        for (int sl = 1; sl < NSLICE; sl++) {
            float m = red_min[sl * 64 + lane];
            int i2 = red_idx[sl * 64 + lane];
            if (m < bm) { bm = m; bi = i2; }  // ascending slice order => first-idx ties
        }
        idx_out[rowbase + lane] = bi;
    }
}

// ---------------------------------------------------------------------------
// Kernel 3: gather + loss partial + transposed write.
// One block per (b,h): 64 w-positions x 128 d.
// ---------------------------------------------------------------------------
__global__ void out_kernel(const float* __restrict__ z,
                           const float* __restrict__ emb,
                           const int* __restrict__ idx,
                           float* __restrict__ out,
                           float* __restrict__ losspart) {
    __shared__ float zq[64 * 129];
    __shared__ int ids[64];
    __shared__ float redl[4];

    const int bid = blockIdx.x;         // b*64 + h
    const int b = bid >> 6;
    const int h = bid & 63;
    const int rowbase = bid * 64;
    const int t = threadIdx.x;

    if (t < 64) ids[t] = idx[rowbase + t];
    __syncthreads();

    // Pass A: coalesced z reads, emb gather (wave-uniform row), loss accum,
    // fill zq tile in LDS.
    const int d = t & 127;
    const int w0 = t >> 7;
    float lsum = 0.f;
#pragma unroll
    for (int wq = 0; wq < 32; wq++) {
        int w = w0 + 2 * wq;
        float e = emb[(size_t)ids[w] * ND + d];
        float zv = z[((size_t)(rowbase + w)) * ND + d];
        float df = e - zv;
        lsum = fmaf(df, df, lsum);
        zq[w * 129 + d] = e;
    }
#pragma unroll
    for (int off = 32; off > 0; off >>= 1) lsum += __shfl_down(lsum, off, 64);
    if ((t & 63) == 0) redl[t >> 6] = lsum;
    __syncthreads();    // also fences zq writes for pass B
    if (t == 0) losspart[bid] = redl[0] + redl[1] + redl[2] + redl[3];

    // Pass B: out[b][d][h][w], lanes sweep w -> coalesced 256B stores.
    const int w = t & 63;
    const int dq = t >> 6;
#pragma unroll
    for (int dd0 = 0; dd0 < 32; dd0++) {
        int dd = dq + 4 * dd0;
        out[(((size_t)b * ND + dd) * NH + h) * NW + w] = zq[w * 129 + dd];
    }
}

// ---------------------------------------------------------------------------
// Kernel 4: final loss reduce
// ---------------------------------------------------------------------------
__global__ void loss_kernel(const float* __restrict__ losspart,
                            float* __restrict__ out) {
    __shared__ float redl[4];
    const int t = threadIdx.x;
    float s = 0.f;
#pragma unroll
    for (int i = 0; i < 4; i++) s += losspart[t + 256 * i];
#pragma unroll
    for (int off = 32; off > 0; off >>= 1) s += __shfl_down(s, off, 64);
    if ((t & 63) == 0) redl[t >> 6] = s;
    __syncthreads();
    if (t == 0) {
        float total = redl[0] + redl[1] + redl[2] + redl[3];
        out[OUT_ELEMS] = 1.25f * total / (float)OUT_ELEMS;
    }
}

// ---------------------------------------------------------------------------
extern "C" void kernel_launch(void* const* d_in, const int* in_sizes, int n_in,
                              void* d_out, int out_size, void* d_ws, size_t ws_size,
                              hipStream_t stream) {
    const float* z = (const float*)d_in[0];      // [16,64,64,128] fp32
    const float* emb = (const float*)d_in[1];    // [4096,128] fp32
    float* out = (float*)d_out;                  // 8388608 + 1 fp32

    char* ws = (char*)d_ws;
    int* ws_idx = (int*)ws;                          // NROWS ints   (256 KB)
    float* ws_enorm = (float*)(ws + 262144);         // NK floats    (16 KB)
    float* ws_losspart = (float*)(ws + 262144 + 16384);  // 1024 floats

    enorm_kernel<<<NK / 4, 256, 0, stream>>>(emb, ws_enorm);
    argmin_kernel<<<NROWS / 64, 256, 0, stream>>>(z, emb, ws_enorm, ws_idx);
    out_kernel<<<NB * NH, 256, 0, stream>>>(z, emb, ws_idx, out, ws_losspart);
    loss_kernel<<<1, 256, 0, stream>>>(ws_losspart, out);
}